// Round 7
// baseline (159.074 us; speedup 1.0000x reference)
//
#include <hip/hip_runtime.h>
#include <hip/hip_bf16.h>
#include <math.h>

// Flash attention, bf16 MFMA 16x16x32, fp32 accumulate. B=2,H=12,S=2048,D=64.
// R16 = R15 + XCD-aware block swizzle (T1), single change.
//  R15 evidence: occupancy counter frozen at ~30% across three geometries ->
//  all waves park on the same stall: the per-tile staging drain. FETCH 62MB vs
//  ~27MB ideal => K/V refetched ~4x because the 8 qb-blocks sharing a (bh,g)
//  K/V panel round-robin onto 8 DIFFERENT XCDs (grid linearized qb-fastest).
//  Fix: 1D grid, id = qb*96 + g*24 + bh => id%8 = bh%8 (96,24 = 0 mod 8), so
//  ALL 32 blocks of a head land on one XCD; per XCD K/V = 3 heads x 512KB =
//  1.5MB < 4MB L2. K/V: one HBM fetch, then L2 hits; staging drain ~900->~200cy,
//  covered by the compute phase.
// Kept: 512-thr/8-wave blocks BQ=256 (R15), V-perm prepass (conflicts=0, R14),
//  in-register P path (R12), K/V LDS dbuf one-barrier-per-tile (R10), GG=4,
//  setprio around MFMA cluster, external reduce.
// NEVER: per-block __threadfence (R13 3x collapse); launch_bounds demanding
//  >4 waves/EU at this reg budget (R11 spill).

#define BB 2
#define HH 12
#define SS 2048
#define DD 64
#define BQ 256
#define BK 64
#define GG 4
#define KG (SS / GG)      // 512 keys per group
#define NTG (KG / BK)     // 8 tiles per group
#define NQB (SS / BQ)     // 8 q-blocks
#define NBH (BB * HH)     // 24 heads
#define LT 76             // prepass transpose stride
#define NROWS (BB * HH * SS)
#define QSCALE 0.1803368801111f   // 0.125 * log2(e)

typedef __attribute__((ext_vector_type(8))) short bf8_t;
typedef __attribute__((ext_vector_type(4))) short bf4_t;
typedef __attribute__((ext_vector_type(4))) float f4_t;
typedef __attribute__((ext_vector_type(4))) unsigned u4_t;
typedef unsigned long long u64;

__device__ __forceinline__ short f2bf(float f) {
    __hip_bfloat16 h = __float2bfloat16(f);
    return *reinterpret_cast<short*>(&h);
}

__device__ __forceinline__ void gl_lds16(const void* g, void* l) {
    __builtin_amdgcn_global_load_lds(
        (const __attribute__((address_space(1))) unsigned*)(g),
        (__attribute__((address_space(3))) unsigned*)(l), 16, 0, 0);
}

// swizzled tile: element (row, c8-chunk) lives at chunk row*8 + (c8 ^ (row&7))
__device__ __forceinline__ bf8_t ldfrag(const unsigned short* buf, int row, int c8) {
    return *(const bf8_t*)&buf[((row << 3) | (c8 ^ (row & 7))) << 3];
}

// ---------- fused prepass ----------
// grid = BB*SS = 4096 blocks x 256.
//  all blocks: pack mask row -> Mbt[b][word][row] (TRANSPOSED for coalescing)
//  bx <  768 : V [bh][s][d] fp32 -> Vt [bh][d][perm(s)] bf16 (64-row tile,
//              keys permuted within each 64-block to the PV frag k-order)
//  768..2304 : K fp32 -> Kb bf16
__global__ __launch_bounds__(256) void prepass(
    const float* __restrict__ V, const float* __restrict__ K,
    const int* __restrict__ M, unsigned short* __restrict__ Vt,
    unsigned short* __restrict__ Kb, u64* __restrict__ Mbt)
{
    __shared__ unsigned short Ts[64][LT];
    const int bx   = blockIdx.x;
    const int tid  = threadIdx.x;
    const int w    = tid >> 6;
    const int lane = tid & 63;
    const int b    = bx >> 11;
    const int row  = bx & 2047;

    {   // mask row bx -> 32 words, transposed layout [b][word][row]
        const int* src = M + (size_t)bx * SS;
        #pragma unroll
        for (int p = 0; p < 8; ++p) {
            int k = p * 256 + w * 64 + lane;
            u64 bm = __ballot(src[k] != 0);
            if (lane == 0)
                Mbt[(size_t)b * 32 * SS + (size_t)(p * 4 + w) * SS + row] = bm;
        }
    }

    if (bx < 768) {
        const int s0 = (bx & 31) * 64;
        const int bh = bx >> 5;
        const float* Vg = V + (size_t)bh * SS * DD;
        #pragma unroll
        for (int pass = 0; pass < 4; ++pass) {
            int c = tid + pass * 256;
            int r = c >> 4, col = (c & 15) * 4;
            float4 v = *(const float4*)(Vg + (size_t)(s0 + r) * DD + col);
            bf4_t p; p.x = f2bf(v.x); p.y = f2bf(v.y); p.z = f2bf(v.z); p.w = f2bf(v.w);
            *(bf4_t*)&Ts[r][col] = p;
        }
        __syncthreads();
        unsigned short* Vo = Vt + (size_t)bh * DD * SS;
        #pragma unroll
        for (int pass = 0; pass < 2; ++pass) {
            int c = tid + pass * 256;
            int d = c >> 3, sc = (c & 7) * 8;
            // permuted key order within the 64-block: output slot sc+u takes
            // source key hh*32 + (u>>2)*16 + qq*4 + (u&3)
            const int hh32 = sc & 32;
            const int qq4  = (sc >> 1) & 12;
            unsigned short t[8];
            #pragma unroll
            for (int u = 0; u < 4; ++u) t[u]     = Ts[hh32 + qq4 + u][d];
            #pragma unroll
            for (int u = 0; u < 4; ++u) t[4 + u] = Ts[hh32 + 16 + qq4 + u][d];
            uint4 o;
            o.x = (unsigned)t[0] | ((unsigned)t[1] << 16);
            o.y = (unsigned)t[2] | ((unsigned)t[3] << 16);
            o.z = (unsigned)t[4] | ((unsigned)t[5] << 16);
            o.w = (unsigned)t[6] | ((unsigned)t[7] << 16);
            *(uint4*)(Vo + (size_t)d * SS + s0 + sc) = o;
        }
    } else if (bx < 2304) {
        size_t i = ((size_t)(bx - 768) * 256 + tid) * 8;
        float4 a = *(const float4*)(K + i);
        float4 b2 = *(const float4*)(K + i + 4);
        uint4 o;
        o.x = (unsigned short)f2bf(a.x)  | ((unsigned)(unsigned short)f2bf(a.y)  << 16);
        o.y = (unsigned short)f2bf(a.z)  | ((unsigned)(unsigned short)f2bf(a.w)  << 16);
        o.z = (unsigned short)f2bf(b2.x) | ((unsigned)(unsigned short)f2bf(b2.y) << 16);
        o.w = (unsigned short)f2bf(b2.z) | ((unsigned)(unsigned short)f2bf(b2.w) << 16);
        *(uint4*)(Kb + i) = o;
    }
}

// ---------- main flash-attention kernel (partial over key group g) ----------
// 1D grid of 768, XCD-swizzled decode: id = qb*96 + g*24 + bh, so id%8 = bh%8
// and every block of a head lands on the same XCD (K/V L2-resident there).
// 512 threads = 8 waves; wave w owns q rows [w*32, w*32+32) of a 256-row block.
__global__ __launch_bounds__(512, 4) void attn_fwd(
    const float* __restrict__ Q, const unsigned short* __restrict__ Kb,
    const unsigned short* __restrict__ Vt, const u64* __restrict__ Mbt,
    float* __restrict__ Opart, float* __restrict__ Lpart)
{
    __shared__ unsigned short Ks[2 * BK * DD];    // 16 KB, swizzled, dbuf
    __shared__ unsigned short Vts[2 * BK * DD];   // 16 KB, swizzled, dbuf

    const int tid  = threadIdx.x;
    const int w    = tid >> 6;        // wave 0..7
    const int lane = tid & 63;
    const int quad = lane >> 4;
    const int l16  = lane & 15;
    const int bx   = blockIdx.x;      // 0..767
    const int qb   = bx / (NBH * GG); // 0..7
    const int rem  = bx % (NBH * GG);
    const int g    = rem / NBH;       // 0..3
    const int bh   = rem % NBH;       // 0..23  (XCD = bh % 8)
    const int q0   = qb * BQ;
    const int b    = bh / HH;
    const int qbase = w * 32;

    const float*          Qg = Q  + (size_t)bh * SS * DD;
    const unsigned short* Kg = Kb + (size_t)bh * SS * DD;
    const unsigned short* Vg = Vt + (size_t)bh * DD * SS;
    float* Og = Opart + ((size_t)g * BB * HH + bh) * SS * DD;
    float* Lg = Lpart + (size_t)g * NROWS + (size_t)bh * SS;

    // ---- loop-invariant Q B-frags (two 16-row groups), 0.125*log2e folded
    bf8_t bq[2][2];
    #pragma unroll
    for (int qf = 0; qf < 2; ++qf)
        #pragma unroll
        for (int ks = 0; ks < 2; ++ks) {
            const float* qp = Qg + (size_t)(q0 + qbase + qf * 16 + l16) * DD
                                 + ks * 32 + quad * 8;
            float4 x = *(const float4*)qp;
            float4 y = *(const float4*)(qp + 4);
            bf8_t f;
            f[0] = f2bf(x.x * QSCALE); f[1] = f2bf(x.y * QSCALE);
            f[2] = f2bf(x.z * QSCALE); f[3] = f2bf(x.w * QSCALE);
            f[4] = f2bf(y.x * QSCALE); f[5] = f2bf(y.y * QSCALE);
            f[6] = f2bf(y.z * QSCALE); f[7] = f2bf(y.w * QSCALE);
            bq[qf][ks] = f;
        }

    // ---- ones column B-frag -> row-sum l in D col 0 (k-order invariant)
    bf8_t onesf;
    {
        short ov = (l16 == 0) ? (short)0x3F80 : (short)0;
        #pragma unroll
        for (int j = 0; j < 8; ++j) onesf[j] = ov;
    }

    f4_t oacc[2][4], lacc[2];
    #pragma unroll
    for (int qf = 0; qf < 2; ++qf) {
        lacc[qf] = (f4_t){0.f, 0.f, 0.f, 0.f};
        #pragma unroll
        for (int nf = 0; nf < 4; ++nf) oacc[qf][nf] = (f4_t){0.f, 0.f, 0.f, 0.f};
    }

    // ---- staging pointers: 512 lanes x 16B = one full 8KB tile per issue.
    //      wave w covers chunk range [w*64, w*64+64)
    const unsigned short* kSrc;
    const unsigned short* vSrc;
    unsigned short*       kDst;
    unsigned short*       vDst;
    {
        const int bc = w * 64;               // wave-uniform chunk base
        const int c  = bc + lane;
        const int r  = c >> 3;
        const int c8 = (c & 7) ^ (r & 7);
        kSrc = Kg + (size_t)(g * KG + r) * DD + c8 * 8;
        vSrc = Vg + (size_t)r * SS + g * KG + c8 * 8;
        kDst = Ks  + bc * 8;
        vDst = Vts + bc * 8;
    }
    const u64* mp[2];
    u64 mpf[2];
    #pragma unroll
    for (int qf = 0; qf < 2; ++qf) {
        mp[qf] = Mbt + (size_t)b * 32 * SS + (size_t)(g * NTG) * SS
                     + q0 + qbase + qf * 16 + l16;
        mpf[qf] = *mp[qf];
    }

    // ---- prologue: stage tile 0 into buffer 0 (the one full-latency wait)
    gl_lds16(kSrc, kDst);
    gl_lds16(vSrc, vDst);
    kSrc += BK * DD;
    vSrc += BK;
    __syncthreads();                     // vmcnt drained: tile 0 visible

    for (int t = 0; t < NTG; ++t) {
        const int cb = (t & 1) * (BK * DD);
        // ---- issue next tile's staging NOW; its vmcnt drain happens at the
        //      end-of-tile barrier, a full compute phase later
        if (t + 1 < NTG) {
            const int nb = ((t + 1) & 1) * (BK * DD);
            gl_lds16(kSrc, kDst + nb);
            gl_lds16(vSrc, vDst + nb);
            kSrc += BK * DD;
            vSrc += BK;
        }
        const u64 cm[2] = {mpf[0] >> (quad * 4), mpf[1] >> (quad * 4)};
        if (t + 1 < NTG) {
            #pragma unroll
            for (int qf = 0; qf < 2; ++qf) {
                mp[qf] += SS;
                mpf[qf] = *mp[qf];       // flies during compute
            }
        }
        const unsigned short* Kst = Ks  + cb;
        const unsigned short* Vst = Vts + cb;

        #pragma unroll
        for (int h = 0; h < 2; ++h) {
            // ---- QK^T + exp; pack P into A-frag words IN REGISTERS
            unsigned aw[2][4];           // [qf][word], fully unrolled indices
            #pragma unroll
            for (int kfh = 0; kfh < 2; ++kfh) {
                const int kf = h * 2 + kfh;
                bf8_t ak0 = ldfrag(Kst, kf * 16 + l16, quad);
                bf8_t ak1 = ldfrag(Kst, kf * 16 + l16, 4 + quad);
                #pragma unroll
                for (int qf = 0; qf < 2; ++qf) {
                    f4_t s = (f4_t){0.f, 0.f, 0.f, 0.f};
                    s = __builtin_amdgcn_mfma_f32_16x16x32_bf16(ak0, bq[qf][0], s, 0, 0, 0);
                    s = __builtin_amdgcn_mfma_f32_16x16x32_bf16(ak1, bq[qf][1], s, 0, 0, 0);
                    // raw v_exp_f32 + mask zero + v_perm truncate-pack
                    float e[4];
                    #pragma unroll
                    for (int r = 0; r < 4; ++r) {
                        float v = __builtin_amdgcn_exp2f(s[r]);
                        e[r] = ((cm[qf] >> (kf * 16 + r)) & 1ull) ? v : 0.f;
                    }
                    aw[qf][kfh * 2 + 0] = __builtin_amdgcn_perm(
                        __float_as_uint(e[1]), __float_as_uint(e[0]), 0x07060302u);
                    aw[qf][kfh * 2 + 1] = __builtin_amdgcn_perm(
                        __float_as_uint(e[3]), __float_as_uint(e[2]), 0x07060302u);
                }
            }
            // ---- A-frags assembled from own lane's values (permuted k-order:
            //      slot j <-> k = h*32 + (j>>2)*16 + quad*4 + (j&3))
            bf8_t ap[2];
            __builtin_amdgcn_s_setprio(1);
            #pragma unroll
            for (int qf = 0; qf < 2; ++qf) {
                u4_t wds = (u4_t){aw[qf][0], aw[qf][1], aw[qf][2], aw[qf][3]};
                ap[qf] = __builtin_bit_cast(bf8_t, wds);
                lacc[qf] = __builtin_amdgcn_mfma_f32_16x16x32_bf16(
                    ap[qf], onesf, lacc[qf], 0, 0, 0);
            }
            // ---- PV for the half; Vt is stored in the SAME permuted k-order
            //      (prepass), so each B-frag is ONE b128 read, shared across qf
            #pragma unroll
            for (int nf = 0; nf < 4; ++nf) {
                bf8_t bv = ldfrag(Vst, nf * 16 + l16, h * 4 + quad);
                #pragma unroll
                for (int qf = 0; qf < 2; ++qf)
                    oacc[qf][nf] = __builtin_amdgcn_mfma_f32_16x16x32_bf16(
                        ap[qf], bv, oacc[qf][nf], 0, 0, 0);
            }
            __builtin_amdgcn_s_setprio(0);
        }
        // ---- ONE barrier per tile: drains this tile's staging (issued a full
        //      compute phase ago) and protects buf[t&1] before restaging
        if (t + 1 < NTG) __syncthreads();
    }

    // ---- epilogue: store unnormalized O partial + l partial
    #pragma unroll
    for (int qf = 0; qf < 2; ++qf) {
        #pragma unroll
        for (int r = 0; r < 4; ++r) {
            const int row = q0 + qbase + qf * 16 + quad * 4 + r;
            #pragma unroll
            for (int nf = 0; nf < 4; ++nf)
                Og[(size_t)row * DD + nf * 16 + l16] = oacc[qf][nf][r];
        }
        if (l16 == 0) {
            #pragma unroll
            for (int r = 0; r < 4; ++r)
                Lg[q0 + qbase + qf * 16 + quad * 4 + r] = lacc[qf][r];
        }
    }
}

// ---------- reduce: O = (sum_g O_g) / (sum_g l_g) ----------
__global__ __launch_bounds__(256) void reduce_o(
    const float* __restrict__ Opart, const float* __restrict__ Lpart,
    float* __restrict__ O)
{
    const size_t idx = (size_t)blockIdx.x * 256 + threadIdx.x;  // float4 units
    const size_t row = idx >> 4;
    const int    c   = (int)(idx & 15) * 4;
    float4 acc = {0.f, 0.f, 0.f, 0.f};
    float  l   = 0.f;
    #pragma unroll
    for (int g = 0; g < GG; ++g) {
        float4 a = *(const float4*)(Opart + ((size_t)g * NROWS + row) * DD + c);
        acc.x += a.x; acc.y += a.y; acc.z += a.z; acc.w += a.w;
        l += Lpart[(size_t)g * NROWS + row];
    }
    const float inv = 1.f / l;
    float4 o;
    o.x = acc.x * inv; o.y = acc.y * inv; o.z = acc.z * inv; o.w = acc.w * inv;
    *(float4*)(O + row * DD + c) = o;
}

extern "C" void kernel_launch(void* const* d_in, const int* in_sizes, int n_in,
                              void* d_out, int out_size, void* d_ws, size_t ws_size,
                              hipStream_t stream) {
    const float* Q = (const float*)d_in[0];
    const float* K = (const float*)d_in[1];
    const float* V = (const float*)d_in[2];
    const int*   M = (const int*)d_in[3];
    float*       O = (float*)d_out;

    unsigned short* Vt    = (unsigned short*)d_ws;                   // 6.29 MB
    unsigned short* Kb    = Vt + (size_t)BB * HH * SS * DD;          // 6.29 MB
    u64*            Mbt   = (u64*)(Kb + (size_t)BB * HH * SS * DD);  // 1.05 MB
    float*          Opart = (float*)(Mbt + (size_t)BB * 32 * SS);    // 50.3 MB
    float*          Lpart = Opart + (size_t)GG * NROWS * DD;         // 0.79 MB

    prepass<<<dim3(BB * SS), 256, 0, stream>>>(V, K, M, Vt, Kb, Mbt);
    attn_fwd<<<dim3(NQB * NBH * GG), 512, 0, stream>>>(Q, Kb, Vt, Mbt,
                                                       Opart, Lpart);
    reduce_o<<<dim3((NROWS * DD / 4) / 256), 256, 0, stream>>>(Opart, Lpart, O);
}

// Round 8
// 147.958 us; speedup vs baseline: 1.0751x; 1.0751x over previous
//
#include <hip/hip_runtime.h>
#include <hip/hip_bf16.h>
#include <math.h>

// Flash attention, bf16 MFMA 16x16x32, fp32 accumulate. B=2,H=12,S=2048,D=64.
// R17 = R16 structure at GG=2 (half the split-K partial traffic).
//  Ledger analysis: ~84us FIXED harness overhead in every config (R9/R12/R13/
//  R14 residuals 83-85us); addressable = kernel time only (attn 48 + prepass
//  ~14 + reduce ~10). attn is within ~10-20% of the m214-extrapolated D=64
//  ceiling (~550-650 TF; we are at 537). Cheapest real us: GG=4's 50MB Opart.
//  GG=2 @ BQ=128/256-thr keeps the proven 768-block balanced grid (16qb x
//  24bh x 2g = 3/CU) while halving attn partial-writes (50->25MB) and
//  reduce_o reads (-25MB => ~10->~6us).
// Kept: in-register P path (R12), V-perm prepass => PV B-frag single b128,
//  conflicts=0 (R14), K/V LDS dbuf one-barrier-per-tile (R10), XCD swizzle
//  id%8=bh%8 => K/V L2-resident, FETCH 22MB (R16), setprio on MFMA cluster.
// NEVER: per-block __threadfence (R13: whole-L2 wb/inv, 3x collapse);
//  launch_bounds demanding >4 waves/EU at this reg budget (R11 spill).

#define BB 2
#define HH 12
#define SS 2048
#define DD 64
#define BQ 128
#define BK 64
#define GG 2
#define KG (SS / GG)      // 1024 keys per group
#define NTG (KG / BK)     // 16 tiles per group
#define NQB (SS / BQ)     // 16 q-blocks
#define NBH (BB * HH)     // 24 heads
#define LT 76             // prepass transpose stride
#define NROWS (BB * HH * SS)
#define QSCALE 0.1803368801111f   // 0.125 * log2(e)

typedef __attribute__((ext_vector_type(8))) short bf8_t;
typedef __attribute__((ext_vector_type(4))) short bf4_t;
typedef __attribute__((ext_vector_type(4))) float f4_t;
typedef __attribute__((ext_vector_type(4))) unsigned u4_t;
typedef unsigned long long u64;

__device__ __forceinline__ short f2bf(float f) {
    __hip_bfloat16 h = __float2bfloat16(f);
    return *reinterpret_cast<short*>(&h);
}

__device__ __forceinline__ void gl_lds16(const void* g, void* l) {
    __builtin_amdgcn_global_load_lds(
        (const __attribute__((address_space(1))) unsigned*)(g),
        (__attribute__((address_space(3))) unsigned*)(l), 16, 0, 0);
}

// swizzled tile: element (row, c8-chunk) lives at chunk row*8 + (c8 ^ (row&7))
__device__ __forceinline__ bf8_t ldfrag(const unsigned short* buf, int row, int c8) {
    return *(const bf8_t*)&buf[((row << 3) | (c8 ^ (row & 7))) << 3];
}

// ---------- fused prepass ----------
// grid = BB*SS = 4096 blocks x 256.
//  all blocks: pack mask row -> Mbt[b][word][row] (TRANSPOSED for coalescing)
//  bx <  768 : V [bh][s][d] fp32 -> Vt [bh][d][perm(s)] bf16 (64-row tile,
//              keys permuted within each 64-block to the PV frag k-order)
//  768..2304 : K fp32 -> Kb bf16
__global__ __launch_bounds__(256) void prepass(
    const float* __restrict__ V, const float* __restrict__ K,
    const int* __restrict__ M, unsigned short* __restrict__ Vt,
    unsigned short* __restrict__ Kb, u64* __restrict__ Mbt)
{
    __shared__ unsigned short Ts[64][LT];
    const int bx   = blockIdx.x;
    const int tid  = threadIdx.x;
    const int w    = tid >> 6;
    const int lane = tid & 63;
    const int b    = bx >> 11;
    const int row  = bx & 2047;

    {   // mask row bx -> 32 words, transposed layout [b][word][row]
        const int* src = M + (size_t)bx * SS;
        #pragma unroll
        for (int p = 0; p < 8; ++p) {
            int k = p * 256 + w * 64 + lane;
            u64 bm = __ballot(src[k] != 0);
            if (lane == 0)
                Mbt[(size_t)b * 32 * SS + (size_t)(p * 4 + w) * SS + row] = bm;
        }
    }

    if (bx < 768) {
        const int s0 = (bx & 31) * 64;
        const int bh = bx >> 5;
        const float* Vg = V + (size_t)bh * SS * DD;
        #pragma unroll
        for (int pass = 0; pass < 4; ++pass) {
            int c = tid + pass * 256;
            int r = c >> 4, col = (c & 15) * 4;
            float4 v = *(const float4*)(Vg + (size_t)(s0 + r) * DD + col);
            bf4_t p; p.x = f2bf(v.x); p.y = f2bf(v.y); p.z = f2bf(v.z); p.w = f2bf(v.w);
            *(bf4_t*)&Ts[r][col] = p;
        }
        __syncthreads();
        unsigned short* Vo = Vt + (size_t)bh * DD * SS;
        #pragma unroll
        for (int pass = 0; pass < 2; ++pass) {
            int c = tid + pass * 256;
            int d = c >> 3, sc = (c & 7) * 8;
            // permuted key order within the 64-block: output slot sc+u takes
            // source key hh*32 + (u>>2)*16 + qq*4 + (u&3)
            const int hh32 = sc & 32;
            const int qq4  = (sc >> 1) & 12;
            unsigned short t[8];
            #pragma unroll
            for (int u = 0; u < 4; ++u) t[u]     = Ts[hh32 + qq4 + u][d];
            #pragma unroll
            for (int u = 0; u < 4; ++u) t[4 + u] = Ts[hh32 + 16 + qq4 + u][d];
            uint4 o;
            o.x = (unsigned)t[0] | ((unsigned)t[1] << 16);
            o.y = (unsigned)t[2] | ((unsigned)t[3] << 16);
            o.z = (unsigned)t[4] | ((unsigned)t[5] << 16);
            o.w = (unsigned)t[6] | ((unsigned)t[7] << 16);
            *(uint4*)(Vo + (size_t)d * SS + s0 + sc) = o;
        }
    } else if (bx < 2304) {
        size_t i = ((size_t)(bx - 768) * 256 + tid) * 8;
        float4 a = *(const float4*)(K + i);
        float4 b2 = *(const float4*)(K + i + 4);
        uint4 o;
        o.x = (unsigned short)f2bf(a.x)  | ((unsigned)(unsigned short)f2bf(a.y)  << 16);
        o.y = (unsigned short)f2bf(a.z)  | ((unsigned)(unsigned short)f2bf(a.w)  << 16);
        o.z = (unsigned short)f2bf(b2.x) | ((unsigned)(unsigned short)f2bf(b2.y) << 16);
        o.w = (unsigned short)f2bf(b2.z) | ((unsigned)(unsigned short)f2bf(b2.w) << 16);
        *(uint4*)(Kb + i) = o;
    }
}

// ---------- main flash-attention kernel (partial over key group g) ----------
// 1D grid of 768, XCD-swizzled decode: id = qb*48 + g*24 + bh, so id%8 = bh%8
// and every block of a head lands on the same XCD (K/V L2-resident there).
// 256 threads = 4 waves; wave w owns q rows [w*32, w*32+32).
__global__ __launch_bounds__(256, 4) void attn_fwd(
    const float* __restrict__ Q, const unsigned short* __restrict__ Kb,
    const unsigned short* __restrict__ Vt, const u64* __restrict__ Mbt,
    float* __restrict__ Opart, float* __restrict__ Lpart)
{
    __shared__ unsigned short Ks[2 * BK * DD];    // 16 KB, swizzled, dbuf
    __shared__ unsigned short Vts[2 * BK * DD];   // 16 KB, swizzled, dbuf

    const int tid  = threadIdx.x;
    const int w    = tid >> 6;        // wave 0..3
    const int lane = tid & 63;
    const int quad = lane >> 4;
    const int l16  = lane & 15;
    const int bx   = blockIdx.x;      // 0..767
    const int qb   = bx / (NBH * GG); // 0..15
    const int rem  = bx % (NBH * GG);
    const int g    = rem / NBH;       // 0..1
    const int bh   = rem % NBH;       // 0..23  (XCD = bh % 8)
    const int q0   = qb * BQ;
    const int b    = bh / HH;
    const int qbase = w * 32;

    const float*          Qg = Q  + (size_t)bh * SS * DD;
    const unsigned short* Kg = Kb + (size_t)bh * SS * DD;
    const unsigned short* Vg = Vt + (size_t)bh * DD * SS;
    float* Og = Opart + ((size_t)g * BB * HH + bh) * SS * DD;
    float* Lg = Lpart + (size_t)g * NROWS + (size_t)bh * SS;

    // ---- loop-invariant Q B-frags (two 16-row groups), 0.125*log2e folded
    bf8_t bq[2][2];
    #pragma unroll
    for (int qf = 0; qf < 2; ++qf)
        #pragma unroll
        for (int ks = 0; ks < 2; ++ks) {
            const float* qp = Qg + (size_t)(q0 + qbase + qf * 16 + l16) * DD
                                 + ks * 32 + quad * 8;
            float4 x = *(const float4*)qp;
            float4 y = *(const float4*)(qp + 4);
            bf8_t f;
            f[0] = f2bf(x.x * QSCALE); f[1] = f2bf(x.y * QSCALE);
            f[2] = f2bf(x.z * QSCALE); f[3] = f2bf(x.w * QSCALE);
            f[4] = f2bf(y.x * QSCALE); f[5] = f2bf(y.y * QSCALE);
            f[6] = f2bf(y.z * QSCALE); f[7] = f2bf(y.w * QSCALE);
            bq[qf][ks] = f;
        }

    // ---- ones column B-frag -> row-sum l in D col 0 (k-order invariant)
    bf8_t onesf;
    {
        short ov = (l16 == 0) ? (short)0x3F80 : (short)0;
        #pragma unroll
        for (int j = 0; j < 8; ++j) onesf[j] = ov;
    }

    f4_t oacc[2][4], lacc[2];
    #pragma unroll
    for (int qf = 0; qf < 2; ++qf) {
        lacc[qf] = (f4_t){0.f, 0.f, 0.f, 0.f};
        #pragma unroll
        for (int nf = 0; nf < 4; ++nf) oacc[qf][nf] = (f4_t){0.f, 0.f, 0.f, 0.f};
    }

    // ---- strength-reduced staging pointers (4 gl_lds16 per wave per tile)
    const unsigned short* kSrc[2];
    const unsigned short* vSrc[2];
    unsigned short*       kDst[2];
    unsigned short*       vDst[2];
    #pragma unroll
    for (int j = 0; j < 2; ++j) {
        const int bc = (w * 2 + j) * 64;     // wave-uniform chunk base
        const int c  = bc + lane;
        const int r  = c >> 3;
        const int c8 = (c & 7) ^ (r & 7);
        kSrc[j] = Kg + (size_t)(g * KG + r) * DD + c8 * 8;
        vSrc[j] = Vg + (size_t)r * SS + g * KG + c8 * 8;
        kDst[j] = Ks  + bc * 8;
        vDst[j] = Vts + bc * 8;
    }
    const u64* mp[2];
    u64 mpf[2];
    #pragma unroll
    for (int qf = 0; qf < 2; ++qf) {
        mp[qf] = Mbt + (size_t)b * 32 * SS + (size_t)(g * NTG) * SS
                     + q0 + qbase + qf * 16 + l16;
        mpf[qf] = *mp[qf];
    }

    // ---- prologue: stage tile 0 into buffer 0 (the one full-latency wait)
    #pragma unroll
    for (int j = 0; j < 2; ++j) {
        gl_lds16(kSrc[j], kDst[j]);
        gl_lds16(vSrc[j], vDst[j]);
        kSrc[j] += BK * DD;
        vSrc[j] += BK;
    }
    __syncthreads();                     // vmcnt drained: tile 0 visible

    for (int t = 0; t < NTG; ++t) {
        const int cb = (t & 1) * (BK * DD);
        // ---- issue next tile's staging NOW; its vmcnt drain happens at the
        //      end-of-tile barrier, a full compute phase later
        if (t + 1 < NTG) {
            const int nb = ((t + 1) & 1) * (BK * DD);
            #pragma unroll
            for (int j = 0; j < 2; ++j) {
                gl_lds16(kSrc[j], kDst[j] + nb);
                gl_lds16(vSrc[j], vDst[j] + nb);
                kSrc[j] += BK * DD;
                vSrc[j] += BK;
            }
        }
        const u64 cm[2] = {mpf[0] >> (quad * 4), mpf[1] >> (quad * 4)};
        if (t + 1 < NTG) {
            #pragma unroll
            for (int qf = 0; qf < 2; ++qf) {
                mp[qf] += SS;
                mpf[qf] = *mp[qf];       // flies during compute
            }
        }
        const unsigned short* Kst = Ks  + cb;
        const unsigned short* Vst = Vts + cb;

        #pragma unroll
        for (int h = 0; h < 2; ++h) {
            // ---- QK^T + exp; pack P into A-frag words IN REGISTERS
            unsigned aw[2][4];           // [qf][word], fully unrolled indices
            #pragma unroll
            for (int kfh = 0; kfh < 2; ++kfh) {
                const int kf = h * 2 + kfh;
                bf8_t ak0 = ldfrag(Kst, kf * 16 + l16, quad);
                bf8_t ak1 = ldfrag(Kst, kf * 16 + l16, 4 + quad);
                #pragma unroll
                for (int qf = 0; qf < 2; ++qf) {
                    f4_t s = (f4_t){0.f, 0.f, 0.f, 0.f};
                    s = __builtin_amdgcn_mfma_f32_16x16x32_bf16(ak0, bq[qf][0], s, 0, 0, 0);
                    s = __builtin_amdgcn_mfma_f32_16x16x32_bf16(ak1, bq[qf][1], s, 0, 0, 0);
                    // raw v_exp_f32 + mask zero + v_perm truncate-pack
                    float e[4];
                    #pragma unroll
                    for (int r = 0; r < 4; ++r) {
                        float v = __builtin_amdgcn_exp2f(s[r]);
                        e[r] = ((cm[qf] >> (kf * 16 + r)) & 1ull) ? v : 0.f;
                    }
                    aw[qf][kfh * 2 + 0] = __builtin_amdgcn_perm(
                        __float_as_uint(e[1]), __float_as_uint(e[0]), 0x07060302u);
                    aw[qf][kfh * 2 + 1] = __builtin_amdgcn_perm(
                        __float_as_uint(e[3]), __float_as_uint(e[2]), 0x07060302u);
                }
            }
            // ---- A-frags assembled from own lane's values (permuted k-order:
            //      slot j <-> k = h*32 + (j>>2)*16 + quad*4 + (j&3))
            bf8_t ap[2];
            __builtin_amdgcn_s_setprio(1);
            #pragma unroll
            for (int qf = 0; qf < 2; ++qf) {
                u4_t wds = (u4_t){aw[qf][0], aw[qf][1], aw[qf][2], aw[qf][3]};
                ap[qf] = __builtin_bit_cast(bf8_t, wds);
                lacc[qf] = __builtin_amdgcn_mfma_f32_16x16x32_bf16(
                    ap[qf], onesf, lacc[qf], 0, 0, 0);
            }
            // ---- PV for the half; Vt is stored in the SAME permuted k-order
            //      (prepass), so each B-frag is ONE b128 read, shared across qf
            #pragma unroll
            for (int nf = 0; nf < 4; ++nf) {
                bf8_t bv = ldfrag(Vst, nf * 16 + l16, h * 4 + quad);
                #pragma unroll
                for (int qf = 0; qf < 2; ++qf)
                    oacc[qf][nf] = __builtin_amdgcn_mfma_f32_16x16x32_bf16(
                        ap[qf], bv, oacc[qf][nf], 0, 0, 0);
            }
            __builtin_amdgcn_s_setprio(0);
        }
        // ---- ONE barrier per tile: drains this tile's staging (issued a full
        //      compute phase ago) and protects buf[t&1] before restaging
        if (t + 1 < NTG) __syncthreads();
    }

    // ---- epilogue: store unnormalized O partial + l partial
    #pragma unroll
    for (int qf = 0; qf < 2; ++qf) {
        #pragma unroll
        for (int r = 0; r < 4; ++r) {
            const int row = q0 + qbase + qf * 16 + quad * 4 + r;
            #pragma unroll
            for (int nf = 0; nf < 4; ++nf)
                Og[(size_t)row * DD + nf * 16 + l16] = oacc[qf][nf][r];
        }
        if (l16 == 0) {
            #pragma unroll
            for (int r = 0; r < 4; ++r)
                Lg[q0 + qbase + qf * 16 + quad * 4 + r] = lacc[qf][r];
        }
    }
}

// ---------- reduce: O = (sum_g O_g) / (sum_g l_g) ----------
__global__ __launch_bounds__(256) void reduce_o(
    const float* __restrict__ Opart, const float* __restrict__ Lpart,
    float* __restrict__ O)
{
    const size_t idx = (size_t)blockIdx.x * 256 + threadIdx.x;  // float4 units
    const size_t row = idx >> 4;
    const int    c   = (int)(idx & 15) * 4;
    float4 acc = {0.f, 0.f, 0.f, 0.f};
    float  l   = 0.f;
    #pragma unroll
    for (int g = 0; g < GG; ++g) {
        float4 a = *(const float4*)(Opart + ((size_t)g * NROWS + row) * DD + c);
        acc.x += a.x; acc.y += a.y; acc.z += a.z; acc.w += a.w;
        l += Lpart[(size_t)g * NROWS + row];
    }
    const float inv = 1.f / l;
    float4 o;
    o.x = acc.x * inv; o.y = acc.y * inv; o.z = acc.z * inv; o.w = acc.w * inv;
    *(float4*)(O + row * DD + c) = o;
}

extern "C" void kernel_launch(void* const* d_in, const int* in_sizes, int n_in,
                              void* d_out, int out_size, void* d_ws, size_t ws_size,
                              hipStream_t stream) {
    const float* Q = (const float*)d_in[0];
    const float* K = (const float*)d_in[1];
    const float* V = (const float*)d_in[2];
    const int*   M = (const int*)d_in[3];
    float*       O = (float*)d_out;

    unsigned short* Vt    = (unsigned short*)d_ws;                   // 6.29 MB
    unsigned short* Kb    = Vt + (size_t)BB * HH * SS * DD;          // 6.29 MB
    u64*            Mbt   = (u64*)(Kb + (size_t)BB * HH * SS * DD);  // 1.05 MB
    float*          Opart = (float*)(Mbt + (size_t)BB * 32 * SS);    // 25.2 MB
    float*          Lpart = Opart + (size_t)GG * NROWS * DD;         // 0.39 MB

    prepass<<<dim3(BB * SS), 256, 0, stream>>>(V, K, M, Vt, Kb, Mbt);
    attn_fwd<<<dim3(NQB * NBH * GG), 256, 0, stream>>>(Q, Kb, Vt, Mbt,
                                                       Opart, Lpart);
    reduce_o<<<dim3((NROWS * DD / 4) / 256), 256, 0, stream>>>(Opart, Lpart, O);
}